// Round 20
// baseline (190.519 us; speedup 1.0000x reference)
//
#include <hip/hip_runtime.h>

#define IN_C 256
#define HIDC 32
#define OUTC 16
#define NPB  256          // nodes per bucket (d_local = 8 bits)
#define MAXBKT 800
#define CAP  16384        // per-bucket csr capacity (mean 8184)
#define EPB  12288        // edges per scatter block
#define EPT  12           // edges per thread (register cache)
#define SEGLEN 96         // slots per (block,bucket) segment; mean 31.4 -> 11.5 sigma

typedef __attribute__((ext_vector_type(8))) short short8;
typedef __attribute__((ext_vector_type(4))) float f32x4;
union S8U4 { short8 s; unsigned u[4]; };

// ---------------- bf16 helpers ---------------------------------------------
__device__ __forceinline__ unsigned bf16pair(float a, float b) {   // RNE pack
    unsigned ua = __float_as_uint(a); ua += 0x7FFF + ((ua >> 16) & 1);
    unsigned ub = __float_as_uint(b); ub += 0x7FFF + ((ub >> 16) & 1);
    return (ua >> 16) | (ub & 0xFFFF0000u);
}
__device__ __forceinline__ float bf16lo(unsigned u) { return __uint_as_float(u << 16); }
__device__ __forceinline__ float bf16hi(unsigned u) { return __uint_as_float(u & 0xFFFF0000u); }
__device__ __forceinline__ unsigned rbf(float a) {                 // bf16 bits, RNE
    unsigned u = __float_as_uint(a);
    u += 0x7FFF + ((u >> 16) & 1);
    return u >> 16;
}
__device__ __forceinline__ void split8(const float* xf, short8& hi, short8& lo) {
    S8U4 H, L;
#pragma unroll
    for (int i = 0; i < 4; ++i) {
        float a = xf[2 * i], b = xf[2 * i + 1];
        unsigned ha = rbf(a), hb = rbf(b);
        float ra = a - __uint_as_float(ha << 16);
        float rb = b - __uint_as_float(hb << 16);
        H.u[i] = ha | (hb << 16);
        L.u[i] = rbf(ra) | (rbf(rb) << 16);
    }
    hi = H.s; lo = L.s;
}

// ---------------- edge index loader (handles int32 or int64 storage) -------
__device__ __forceinline__ int edge_at(const int* __restrict__ ei, long long idx, int is64) {
    return is64 ? ei[idx << 1] : ei[idx];
}

// ---------------- init: detect dtype + W1 fragments ------------------------
__global__ void k_init(const int* __restrict__ ei, int* __restrict__ flag,
                       const float* __restrict__ W1, unsigned short* __restrict__ wf) {
    if (blockIdx.x == 0) {
        __shared__ int nz;
        if (threadIdx.x == 0) nz = 0;
        __syncthreads();
        if (ei[2 * threadIdx.x + 1] != 0) atomicOr(&nz, 1);
        __syncthreads();
        if (threadIdx.x == 0) *flag = (nz == 0) ? 1 : 0;
    } else {
        int idx = (blockIdx.x - 1) * 256 + threadIdx.x;   // 0..2047
        int lane = idx & 63;
        int part = (idx >> 6) & 1;
        int tile = (idx >> 7) & 1;
        int s    = idx >> 8;
        int col = tile * 16 + (lane & 15);
        int k0  = s * 32 + (lane >> 4) * 8;
#pragma unroll
        for (int j = 0; j < 8; ++j) {
            float v = W1[(long long)(k0 + j) * HIDC + col];
            unsigned h = rbf(v);
            float r = v - __uint_as_float(h << 16);
            wf[(long long)idx * 8 + j] = (unsigned short)(part == 0 ? h : rbf(r));
        }
    }
}

// ---------------- super-kernel: edge scatter ∥ MFMA gemm1 ------------------
// Round-20 scatter: DETERMINISTIC placement — each (block,bucket) owns a
// fixed 64B-aligned 96-slot segment. No global atomics, no reserve barrier,
// no cross-XCD cache-line sharing on packed writes. Per-block counts to cntm.
__global__ __launch_bounds__(1024) void k_super(const int* __restrict__ ei, long long E,
                                                const int* __restrict__ flag,
                                                int* __restrict__ cntm,
                                                unsigned* __restrict__ packed, int nbkt, int nsb,
                                                const float* __restrict__ x,
                                                const unsigned short* __restrict__ wf,
                                                unsigned short* __restrict__ h1b_us, int n) {
    if ((int)blockIdx.x < nsb) {
        __shared__ int hist[MAXBKT];
        int is64 = *flag;
        for (int i = threadIdx.x; i < nbkt; i += 1024) hist[i] = 0;
        __syncthreads();
        long long lo = (long long)blockIdx.x * EPB;
        int m = (int)((E - lo) < EPB ? (E - lo) : EPB);
        unsigned ew[EPT];
        int      eb[EPT];
#pragma unroll
        for (int j = 0; j < EPT; ++j) {
            int i = j * 1024 + (int)threadIdx.x;
            eb[j] = -1;
            if (i < m) {
                int s = edge_at(ei, lo + i, is64);
                int d = edge_at(ei, E + lo + i, is64);
                ew[j] = (unsigned)s | ((unsigned)(d & (NPB - 1)) << 20);
                eb[j] = d >> 8;
                atomicAdd(&hist[eb[j]], 1);
            }
        }
        __syncthreads();
        for (int b = threadIdx.x; b < nbkt; b += 1024) {
            cntm[(long long)blockIdx.x * nbkt + b] = hist[b];
            hist[b] = 0;                      // reuse as local cursor
        }
        __syncthreads();
        const long long segrow = (long long)nsb * SEGLEN;
#pragma unroll
        for (int j = 0; j < EPT; ++j) {
            if (eb[j] >= 0) {
                int r = atomicAdd(&hist[eb[j]], 1);
                packed[(long long)eb[j] * segrow + (long long)blockIdx.x * SEGLEN + r] = ew[j];
            }
        }
    } else {
        // ---- gemm1 via MFMA (unscaled output; rescale in k_bucket_csr) ----
        const int gb = (int)blockIdx.x - nsb;
        const int t = (int)threadIdx.x;
        const int l = t & 63;
        const int w = t >> 6;                                  // 0..15 waves
        const long long nb0 = (long long)gb * 256 + w * 16;
        const int kg = l >> 4;
        const long long nodeA = nb0 + (l & 15);
        const bool loadA = nodeA < n;
        f32x4 acc0 = {0.f, 0.f, 0.f, 0.f}, acc1 = {0.f, 0.f, 0.f, 0.f};
#pragma unroll
        for (int s = 0; s < 8; ++s) {
            float xf[8];
            if (loadA) {
                float4 v0 = *(const float4*)(x + nodeA * IN_C + s * 32 + kg * 8);
                float4 v1 = *(const float4*)(x + nodeA * IN_C + s * 32 + kg * 8 + 4);
                xf[0] = v0.x; xf[1] = v0.y; xf[2] = v0.z; xf[3] = v0.w;
                xf[4] = v1.x; xf[5] = v1.y; xf[6] = v1.z; xf[7] = v1.w;
            } else {
#pragma unroll
                for (int j = 0; j < 8; ++j) xf[j] = 0.f;
            }
            short8 ah, al;
            split8(xf, ah, al);
            const unsigned short* base = wf + ((long long)(s * 4) * 64 + l) * 8;
            short8 bh0 = *(const short8*)(base);
            short8 bl0 = *(const short8*)(base + 64 * 8);
            short8 bh1 = *(const short8*)(base + 2 * 64 * 8);
            short8 bl1 = *(const short8*)(base + 3 * 64 * 8);
            acc0 = __builtin_amdgcn_mfma_f32_16x16x32_bf16(ah, bh0, acc0, 0, 0, 0);
            acc0 = __builtin_amdgcn_mfma_f32_16x16x32_bf16(ah, bl0, acc0, 0, 0, 0);
            acc0 = __builtin_amdgcn_mfma_f32_16x16x32_bf16(al, bh0, acc0, 0, 0, 0);
            acc1 = __builtin_amdgcn_mfma_f32_16x16x32_bf16(ah, bh1, acc1, 0, 0, 0);
            acc1 = __builtin_amdgcn_mfma_f32_16x16x32_bf16(ah, bl1, acc1, 0, 0, 0);
            acc1 = __builtin_amdgcn_mfma_f32_16x16x32_bf16(al, bh1, acc1, 0, 0, 0);
        }
        // D layout (m89-verified): row = (l>>4)*4 + r, col = l&15
#pragma unroll
        for (int r = 0; r < 4; ++r) {
            long long nd = nb0 + (l >> 4) * 4 + r;
            if (nd < n) {
                h1b_us[nd * 32 + (l & 15)]      = (unsigned short)rbf(acc0[r]);
                h1b_us[nd * 32 + 16 + (l & 15)] = (unsigned short)rbf(acc1[r]);
            }
        }
    }
}

// ---------------- per-bucket segmented sort -> CSR + dinv + h1b rescale ----
// Reads the bucket's nsb fixed segments (lengths from cntm), two walk passes
// via binary search over the segment prefix.
__global__ __launch_bounds__(256) void k_bucket_csr(const unsigned* __restrict__ packed,
                                                    const int* __restrict__ cntm, int nsb,
                                                    int* __restrict__ csr_src,
                                                    int* __restrict__ ptr,
                                                    int* __restrict__ cnt,
                                                    float* __restrict__ dinv,
                                                    unsigned* __restrict__ h1b, int n) {
    __shared__ int hist[NPB];
    __shared__ int off[NPB];
    __shared__ int P[513];
    __shared__ int sm[256];
    const int b = blockIdx.x;
    const int nbkt = gridDim.x;
    const int t = threadIdx.x;
    // segment counts -> exclusive prefix P[0..nsb], P[nsb]=m (2 elems/thread)
    int e0 = (2 * t < nsb) ? cntm[(long long)(2 * t) * nbkt + b] : 0;
    int e1 = (2 * t + 1 < nsb) ? cntm[(long long)(2 * t + 1) * nbkt + b] : 0;
    int pv = e0 + e1;
    sm[t] = pv;
    hist[t] = 0;
    __syncthreads();
    for (int o = 1; o < 256; o <<= 1) {
        int v = (t >= o) ? sm[t - o] : 0;
        __syncthreads();
        sm[t] += v;
        __syncthreads();
    }
    int pb = sm[t] - pv;
    if (2 * t < nsb)     P[2 * t]     = pb;
    if (2 * t + 1 < nsb) P[2 * t + 1] = pb + e0;
    if (t == 255) P[nsb] = sm[255];
    __syncthreads();
    const int m = P[nsb];
    const long long segrow = (long long)nsb * SEGLEN;
    const long long pbase = (long long)b * segrow;
    // pass 1: node histogram
    for (int g = t; g < m; g += 256) {
        int lo2 = 0, hi2 = nsb;
        while (hi2 - lo2 > 1) { int mid = (lo2 + hi2) >> 1; if (P[mid] <= g) lo2 = mid; else hi2 = mid; }
        unsigned w = packed[pbase + (long long)lo2 * SEGLEN + (g - P[lo2])];
        atomicAdd(&hist[w >> 20], 1);
    }
    __syncthreads();
    off[t] = hist[t];
    __syncthreads();
    for (int o = 1; o < NPB; o <<= 1) {
        int v = (t >= o) ? off[t - o] : 0;
        __syncthreads();
        off[t] += v;
        __syncthreads();
    }
    long long node = (long long)b * NPB + t;
    int base = b * CAP;
    {
        int exc = off[t] - hist[t];
        if (node < n) {
            float di = rsqrtf((float)hist[t] + 1.0f);
            ptr[node]  = base + exc;
            cnt[node]  = hist[t];
            dinv[node] = di;
            unsigned* row = h1b + node * 16;
#pragma unroll
            for (int q = 0; q < 16; ++q) {
                unsigned u = row[q];
                row[q] = bf16pair(bf16lo(u) * di, bf16hi(u) * di);
            }
        }
        hist[t] = exc;                        // reuse as node cursor
    }
    __syncthreads();
    // pass 2: place into csr
    for (int g = t; g < m; g += 256) {
        int lo2 = 0, hi2 = nsb;
        while (hi2 - lo2 > 1) { int mid = (lo2 + hi2) >> 1; if (P[mid] <= g) lo2 = mid; else hi2 = mid; }
        unsigned w = packed[pbase + (long long)lo2 * SEGLEN + (g - P[lo2])];
        int r = atomicAdd(&hist[w >> 20], 1);
        csr_src[base + r] = (int)(w & 0xFFFFF);
    }
}

// ---------------- fused layer-1 aggregation + gemm2 ------------------------
__global__ __launch_bounds__(256) void k_agg1g2(const int* __restrict__ ptr,
                                                const int* __restrict__ cnt,
                                                const int* __restrict__ csr_src,
                                                const float* __restrict__ dinv,
                                                const unsigned* __restrict__ h1b,
                                                const float* __restrict__ b1,
                                                const float* __restrict__ W2,
                                                unsigned* __restrict__ h2b, int n) {
    __shared__ float hs[16][33];
    __shared__ float wl2[32][17];
    const int t = threadIdx.x;
    for (int i = t; i < HIDC * OUTC; i += 256) wl2[i >> 4][i & 15] = W2[i];
    const int nl = t >> 4;
    const int cp = t & 15;
    const long long node = (long long)blockIdx.x * 16 + nl;
    float vL = 0.f, vH = 0.f;
    if (node < n) {
        unsigned us = h1b[node * 16 + cp];
        float accL = bf16lo(us), accH = bf16hi(us);
        int st = ptr[node], deg = cnt[node];
        int j = 0;
        for (; j + 3 < deg; j += 4) {
            int s0 = csr_src[st + j], s1 = csr_src[st + j + 1];
            int s2 = csr_src[st + j + 2], s3 = csr_src[st + j + 3];
            unsigned u0 = h1b[(long long)s0 * 16 + cp];
            unsigned u1 = h1b[(long long)s1 * 16 + cp];
            unsigned u2 = h1b[(long long)s2 * 16 + cp];
            unsigned u3 = h1b[(long long)s3 * 16 + cp];
            accL += (bf16lo(u0) + bf16lo(u1)) + (bf16lo(u2) + bf16lo(u3));
            accH += (bf16hi(u0) + bf16hi(u1)) + (bf16hi(u2) + bf16hi(u3));
        }
        for (; j < deg; ++j) {
            unsigned u = h1b[(long long)csr_src[st + j] * 16 + cp];
            accL += bf16lo(u); accH += bf16hi(u);
        }
        float di = dinv[node];
        vL = accL * di + b1[2 * cp];
        vH = accH * di + b1[2 * cp + 1];
        vL = vL > 0.f ? vL : 0.f;
        vH = vH > 0.f ? vH : 0.f;
    }
    hs[nl][2 * cp]     = vL;
    hs[nl][2 * cp + 1] = vH;
    __syncthreads();
    if (t < 128) {
        int nl2 = t >> 3;
        int op  = t & 7;
        long long nd = (long long)blockIdx.x * 16 + nl2;
        if (nd < n) {
            float o0 = 0.f, o1 = 0.f;
#pragma unroll
            for (int k = 0; k < HIDC; ++k) {
                float h = hs[nl2][k];
                o0 = fmaf(h, wl2[k][2 * op],     o0);
                o1 = fmaf(h, wl2[k][2 * op + 1], o1);
            }
            float di = dinv[nd];
            h2b[nd * 8 + op] = bf16pair(o0 * di, o1 * di);
        }
    }
}

// ---------------- layer-2 pull aggregation (bf16 gathers) -> d_out ---------
__global__ __launch_bounds__(256) void k_agg2csr(const int* __restrict__ ptr,
                                                 const int* __restrict__ cnt,
                                                 const int* __restrict__ csr_src,
                                                 const float* __restrict__ dinv,
                                                 const unsigned* __restrict__ h2b,
                                                 const float* __restrict__ b2,
                                                 float* __restrict__ out, int n) {
    long long g = (long long)blockIdx.x * blockDim.x + threadIdx.x;
    int node = (int)(g >> 3);
    int cp = (int)(g & 7);
    if (node >= n) return;
    unsigned us = h2b[(long long)node * 8 + cp];
    float accL = bf16lo(us), accH = bf16hi(us);
    int st = ptr[node], deg = cnt[node];
    int j = 0;
    for (; j + 3 < deg; j += 4) {
        int s0 = csr_src[st + j], s1 = csr_src[st + j + 1];
        int s2 = csr_src[st + j + 2], s3 = csr_src[st + j + 3];
        unsigned u0 = h2b[(long long)s0 * 8 + cp];
        unsigned u1 = h2b[(long long)s1 * 8 + cp];
        unsigned u2 = h2b[(long long)s2 * 8 + cp];
        unsigned u3 = h2b[(long long)s3 * 8 + cp];
        accL += (bf16lo(u0) + bf16lo(u1)) + (bf16lo(u2) + bf16lo(u3));
        accH += (bf16hi(u0) + bf16hi(u1)) + (bf16hi(u2) + bf16hi(u3));
    }
    for (; j < deg; ++j) {
        unsigned u = h2b[(long long)csr_src[st + j] * 8 + cp];
        accL += bf16lo(u); accH += bf16hi(u);
    }
    float di = dinv[node];
    *(float2*)(out + (long long)node * OUTC + 2 * cp) =
        make_float2(accL * di + b2[2 * cp], accH * di + b2[2 * cp + 1]);
}

extern "C" void kernel_launch(void* const* d_in, const int* in_sizes, int n_in,
                              void* d_out, int out_size, void* d_ws, size_t ws_size,
                              hipStream_t stream) {
    const float* x  = (const float*)d_in[0];
    const int*   ei = (const int*)d_in[1];
    const float* W1 = (const float*)d_in[2];
    const float* b1 = (const float*)d_in[3];
    const float* W2 = (const float*)d_in[4];
    const float* b2 = (const float*)d_in[5];
    const int n = in_sizes[0] / IN_C;            // 100000
    const long long E = in_sizes[1] / 2;         // 3200000
    float* out = (float*)d_out;

    const int nbkt = (n + NPB - 1) / NPB;        // 391
    const int nsb  = (int)((E + EPB - 1) / EPB); // 261 scatter blocks
    const int ngb  = (n + 255) / 256;            // 391 gemm1 blocks

    char* ws = (char*)d_ws;
    size_t off = 0;
    auto alloc = [&](size_t bytes) { void* p = ws + off; off += (bytes + 255) & ~(size_t)255; return p; };
    int*      flag     = (int*)alloc(256);
    float*    dinv     = (float*)alloc((size_t)n * 4);
    int*      cnt      = (int*)alloc((size_t)n * 4);
    int*      ptr      = (int*)alloc((size_t)n * 4);
    int*      cntm     = (int*)alloc((size_t)nsb * nbkt * 4);             // 408 KB
    unsigned* packed   = (unsigned*)alloc((size_t)nbkt * nsb * SEGLEN * 4); // 39.2 MB
    int*      csr_src  = (int*)alloc((size_t)nbkt * CAP * 4);             // 25.6 MB
    unsigned short* wf = (unsigned short*)alloc(8 * 2 * 2 * 64 * 8 * 2);  // 32 KB
    unsigned* h1b      = (unsigned*)alloc((size_t)n * (HIDC / 2) * 4);    // bf16 [n][32]
    unsigned* h2b      = (unsigned*)alloc((size_t)n * (OUTC / 2) * 4);    // bf16 [n][16]

    k_init<<<9, 256, 0, stream>>>(ei, flag, W1, wf);
    k_super<<<nsb + ngb, 1024, 0, stream>>>(ei, E, flag, cntm, packed, nbkt, nsb,
                                            x, wf, (unsigned short*)h1b, n);
    k_bucket_csr<<<nbkt, NPB, 0, stream>>>(packed, cntm, nsb, csr_src, ptr, cnt, dinv, h1b, n);
    k_agg1g2<<<(n + 15) / 16, 256, 0, stream>>>(ptr, cnt, csr_src, dinv, h1b, b1, W2, h2b, n);
    k_agg2csr<<<(int)(((long long)n * 8 + 255) / 256), 256, 0, stream>>>(
        ptr, cnt, csr_src, dinv, h2b, b2, out, n);
}

// Round 21
// 159.309 us; speedup vs baseline: 1.1959x; 1.1959x over previous
//
#include <hip/hip_runtime.h>

#define IN_C 256
#define HIDC 32
#define OUTC 16
#define NPB  256          // nodes per bucket (d_local = 8 bits)
#define MAXBKT 800
#define CAP  16384        // per-bucket packed capacity (mean 8184 -> 90 sigma safe)
#define EPB  12288        // edges per scatter block
#define EPT  12           // edges per thread (register cache)

typedef __attribute__((ext_vector_type(8))) short short8;
typedef __attribute__((ext_vector_type(4))) float f32x4;
union S8U4 { short8 s; unsigned u[4]; };

// ---------------- bf16 helpers ---------------------------------------------
__device__ __forceinline__ unsigned bf16pair(float a, float b) {   // RNE pack
    unsigned ua = __float_as_uint(a); ua += 0x7FFF + ((ua >> 16) & 1);
    unsigned ub = __float_as_uint(b); ub += 0x7FFF + ((ub >> 16) & 1);
    return (ua >> 16) | (ub & 0xFFFF0000u);
}
__device__ __forceinline__ float bf16lo(unsigned u) { return __uint_as_float(u << 16); }
__device__ __forceinline__ float bf16hi(unsigned u) { return __uint_as_float(u & 0xFFFF0000u); }
__device__ __forceinline__ unsigned rbf(float a) {                 // bf16 bits, RNE
    unsigned u = __float_as_uint(a);
    u += 0x7FFF + ((u >> 16) & 1);
    return u >> 16;
}
__device__ __forceinline__ void split8(const float* xf, short8& hi, short8& lo) {
    S8U4 H, L;
#pragma unroll
    for (int i = 0; i < 4; ++i) {
        float a = xf[2 * i], b = xf[2 * i + 1];
        unsigned ha = rbf(a), hb = rbf(b);
        float ra = a - __uint_as_float(ha << 16);
        float rb = b - __uint_as_float(hb << 16);
        H.u[i] = ha | (hb << 16);
        L.u[i] = rbf(ra) | (rbf(rb) << 16);
    }
    hi = H.s; lo = L.s;
}

// ---------------- edge index loader (handles int32 or int64 storage) -------
__device__ __forceinline__ int edge_at(const int* __restrict__ ei, long long idx, int is64) {
    return is64 ? ei[idx << 1] : ei[idx];
}

// ---------------- init: detect dtype + cursor init + W1 fragments ----------
__global__ void k_init(const int* __restrict__ ei, int* __restrict__ flag,
                       int* __restrict__ bkt_cur, int nbkt,
                       const float* __restrict__ W1, unsigned short* __restrict__ wf) {
    if (blockIdx.x == 0) {
        __shared__ int nz;
        if (threadIdx.x == 0) nz = 0;
        __syncthreads();
        if (ei[2 * threadIdx.x + 1] != 0) atomicOr(&nz, 1);
        for (int i = threadIdx.x; i < nbkt; i += 256) bkt_cur[i] = i * CAP;
        __syncthreads();
        if (threadIdx.x == 0) *flag = (nz == 0) ? 1 : 0;
    } else {
        int idx = (blockIdx.x - 1) * 256 + threadIdx.x;   // 0..2047
        int lane = idx & 63;
        int part = (idx >> 6) & 1;
        int tile = (idx >> 7) & 1;
        int s    = idx >> 8;
        int col = tile * 16 + (lane & 15);
        int k0  = s * 32 + (lane >> 4) * 8;
#pragma unroll
        for (int j = 0; j < 8; ++j) {
            float v = W1[(long long)(k0 + j) * HIDC + col];
            unsigned h = rbf(v);
            float r = v - __uint_as_float(h << 16);
            wf[(long long)idx * 8 + j] = (unsigned short)(part == 0 ? h : rbf(r));
        }
    }
}

// ---------------- super-kernel: edge scatter ∥ MFMA gemm1 (round-19) -------
__global__ __launch_bounds__(1024) void k_super(const int* __restrict__ ei, long long E,
                                                const int* __restrict__ flag,
                                                int* __restrict__ bkt_cur,
                                                unsigned* __restrict__ packed, int nbkt, int nsb,
                                                const float* __restrict__ x,
                                                const unsigned short* __restrict__ wf,
                                                unsigned short* __restrict__ h1b_us, int n) {
    if ((int)blockIdx.x < nsb) {
        __shared__ int hist[MAXBKT];
        int is64 = *flag;
        for (int i = threadIdx.x; i < nbkt; i += 1024) hist[i] = 0;
        __syncthreads();
        long long lo = (long long)blockIdx.x * EPB;
        int m = (int)((E - lo) < EPB ? (E - lo) : EPB);
        unsigned ew[EPT];
        int      eb[EPT];
#pragma unroll
        for (int j = 0; j < EPT; ++j) {
            int i = j * 1024 + (int)threadIdx.x;
            eb[j] = -1;
            if (i < m) {
                int s = edge_at(ei, lo + i, is64);
                int d = edge_at(ei, E + lo + i, is64);
                ew[j] = (unsigned)s | ((unsigned)(d & (NPB - 1)) << 20);
                eb[j] = d >> 8;
                atomicAdd(&hist[eb[j]], 1);
            }
        }
        __syncthreads();
        for (int b = threadIdx.x; b < nbkt; b += 1024) {
            int c = hist[b];
            hist[b] = c ? atomicAdd(&bkt_cur[b], c) : 0;
        }
        __syncthreads();
#pragma unroll
        for (int j = 0; j < EPT; ++j) {
            if (eb[j] >= 0) {
                int slot = atomicAdd(&hist[eb[j]], 1);
                packed[slot] = ew[j];
            }
        }
    } else {
        // ---- gemm1 via MFMA (unscaled output; rescale in k_bucket_csr) ----
        const int gb = (int)blockIdx.x - nsb;
        const int t = (int)threadIdx.x;
        const int l = t & 63;
        const int w = t >> 6;                                  // 0..15 waves
        const long long nb0 = (long long)gb * 256 + w * 16;
        const int kg = l >> 4;
        const long long nodeA = nb0 + (l & 15);
        const bool loadA = nodeA < n;
        f32x4 acc0 = {0.f, 0.f, 0.f, 0.f}, acc1 = {0.f, 0.f, 0.f, 0.f};
#pragma unroll
        for (int s = 0; s < 8; ++s) {
            float xf[8];
            if (loadA) {
                float4 v0 = *(const float4*)(x + nodeA * IN_C + s * 32 + kg * 8);
                float4 v1 = *(const float4*)(x + nodeA * IN_C + s * 32 + kg * 8 + 4);
                xf[0] = v0.x; xf[1] = v0.y; xf[2] = v0.z; xf[3] = v0.w;
                xf[4] = v1.x; xf[5] = v1.y; xf[6] = v1.z; xf[7] = v1.w;
            } else {
#pragma unroll
                for (int j = 0; j < 8; ++j) xf[j] = 0.f;
            }
            short8 ah, al;
            split8(xf, ah, al);
            const unsigned short* base = wf + ((long long)(s * 4) * 64 + l) * 8;
            short8 bh0 = *(const short8*)(base);
            short8 bl0 = *(const short8*)(base + 64 * 8);
            short8 bh1 = *(const short8*)(base + 2 * 64 * 8);
            short8 bl1 = *(const short8*)(base + 3 * 64 * 8);
            acc0 = __builtin_amdgcn_mfma_f32_16x16x32_bf16(ah, bh0, acc0, 0, 0, 0);
            acc0 = __builtin_amdgcn_mfma_f32_16x16x32_bf16(ah, bl0, acc0, 0, 0, 0);
            acc0 = __builtin_amdgcn_mfma_f32_16x16x32_bf16(al, bh0, acc0, 0, 0, 0);
            acc1 = __builtin_amdgcn_mfma_f32_16x16x32_bf16(ah, bh1, acc1, 0, 0, 0);
            acc1 = __builtin_amdgcn_mfma_f32_16x16x32_bf16(ah, bl1, acc1, 0, 0, 0);
            acc1 = __builtin_amdgcn_mfma_f32_16x16x32_bf16(al, bh1, acc1, 0, 0, 0);
        }
        // D layout (m89-verified): row = (l>>4)*4 + r, col = l&15
#pragma unroll
        for (int r = 0; r < 4; ++r) {
            long long nd = nb0 + (l >> 4) * 4 + r;
            if (nd < n) {
                h1b_us[nd * 32 + (l & 15)]      = (unsigned short)rbf(acc0[r]);
                h1b_us[nd * 32 + 16 + (l & 15)] = (unsigned short)rbf(acc1[r]);
            }
        }
    }
}

// ---------------- per-bucket counting sort -> CSR + dinv + h1b rescale -----
__global__ __launch_bounds__(256) void k_bucket_csr(const unsigned* __restrict__ packed,
                                                    const int* __restrict__ bkt_cur,
                                                    int* __restrict__ csr_src,
                                                    int* __restrict__ ptr,
                                                    int* __restrict__ cnt,
                                                    float* __restrict__ dinv,
                                                    unsigned* __restrict__ h1b, int n) {
    __shared__ int hist[NPB];
    __shared__ int off[NPB];
    hist[threadIdx.x] = 0;
    __syncthreads();
    int base = blockIdx.x * CAP;
    int m = bkt_cur[blockIdx.x] - base;
    for (int i = threadIdx.x; i < m; i += 256)
        atomicAdd(&hist[packed[base + i] >> 20], 1);
    __syncthreads();
    off[threadIdx.x] = hist[threadIdx.x];
    __syncthreads();
    for (int o = 1; o < NPB; o <<= 1) {
        int v = (threadIdx.x >= o) ? off[threadIdx.x - o] : 0;
        __syncthreads();
        off[threadIdx.x] += v;
        __syncthreads();
    }
    long long node = (long long)blockIdx.x * NPB + threadIdx.x;
    {
        int exc = off[threadIdx.x] - hist[threadIdx.x];
        if (node < n) {
            float di = rsqrtf((float)hist[threadIdx.x] + 1.0f);
            ptr[node]  = base + exc;
            cnt[node]  = hist[threadIdx.x];
            dinv[node] = di;
            // rescale unscaled gemm1 output: h1b[node] *= di (bf16 in, bf16 out)
            unsigned* row = h1b + node * 16;
#pragma unroll
            for (int q = 0; q < 16; ++q) {
                unsigned u = row[q];
                row[q] = bf16pair(bf16lo(u) * di, bf16hi(u) * di);
            }
        }
        hist[threadIdx.x] = exc;
    }
    __syncthreads();
    for (int i = threadIdx.x; i < m; i += 256) {
        unsigned w = packed[base + i];
        int r = atomicAdd(&hist[w >> 20], 1);
        csr_src[base + r] = (int)(w & 0xFFFFF);
    }
}

// ---------------- fused layer-1 aggregation + gemm2 (8B gathers) -----------
// Round-21: 8 lanes/node, each lane gathers uint2 (4 bf16 channels) -> half
// the gather instructions per edge at identical bytes (MLP-bound gathers).
// 32 nodes/block; phase B = exact 256 threads (32 nodes x 8 out-pairs).
__global__ __launch_bounds__(256) void k_agg1g2(const int* __restrict__ ptr,
                                                const int* __restrict__ cnt,
                                                const int* __restrict__ csr_src,
                                                const float* __restrict__ dinv,
                                                const unsigned* __restrict__ h1b,
                                                const float* __restrict__ b1,
                                                const float* __restrict__ W2,
                                                unsigned* __restrict__ h2b, int n) {
    __shared__ float hs[32][33];
    __shared__ float wl2[32][17];
    const int t = threadIdx.x;
    for (int i = t; i < HIDC * OUTC; i += 256) wl2[i >> 4][i & 15] = W2[i];
    const int nl = t >> 3;               // 0..31 node-local
    const int qp = t & 7;                // channel quad-pair: ch 4qp..4qp+3
    const long long node = (long long)blockIdx.x * 32 + nl;
    const uint2* __restrict__ h1v = (const uint2*)h1b;   // 8 uint2 per node
    float v0 = 0.f, v1 = 0.f, v2 = 0.f, v3 = 0.f;
    if (node < n) {
        uint2 us = h1v[node * 8 + qp];
        float a0 = bf16lo(us.x), a1 = bf16hi(us.x);
        float a2 = bf16lo(us.y), a3 = bf16hi(us.y);
        int st = ptr[node], deg = cnt[node];
        int j = 0;
        for (; j + 3 < deg; j += 4) {
            int s0 = csr_src[st + j], s1 = csr_src[st + j + 1];
            int s2 = csr_src[st + j + 2], s3 = csr_src[st + j + 3];
            uint2 u0 = h1v[(long long)s0 * 8 + qp];
            uint2 u1 = h1v[(long long)s1 * 8 + qp];
            uint2 u2 = h1v[(long long)s2 * 8 + qp];
            uint2 u3 = h1v[(long long)s3 * 8 + qp];
            a0 += (bf16lo(u0.x) + bf16lo(u1.x)) + (bf16lo(u2.x) + bf16lo(u3.x));
            a1 += (bf16hi(u0.x) + bf16hi(u1.x)) + (bf16hi(u2.x) + bf16hi(u3.x));
            a2 += (bf16lo(u0.y) + bf16lo(u1.y)) + (bf16lo(u2.y) + bf16lo(u3.y));
            a3 += (bf16hi(u0.y) + bf16hi(u1.y)) + (bf16hi(u2.y) + bf16hi(u3.y));
        }
        for (; j < deg; ++j) {
            uint2 u = h1v[(long long)csr_src[st + j] * 8 + qp];
            a0 += bf16lo(u.x); a1 += bf16hi(u.x);
            a2 += bf16lo(u.y); a3 += bf16hi(u.y);
        }
        float di = dinv[node];
        v0 = a0 * di + b1[4 * qp];     v0 = v0 > 0.f ? v0 : 0.f;
        v1 = a1 * di + b1[4 * qp + 1]; v1 = v1 > 0.f ? v1 : 0.f;
        v2 = a2 * di + b1[4 * qp + 2]; v2 = v2 > 0.f ? v2 : 0.f;
        v3 = a3 * di + b1[4 * qp + 3]; v3 = v3 > 0.f ? v3 : 0.f;
    }
    hs[nl][4 * qp]     = v0;
    hs[nl][4 * qp + 1] = v1;
    hs[nl][4 * qp + 2] = v2;
    hs[nl][4 * qp + 3] = v3;
    __syncthreads();
    {
        int nl2 = t >> 3;                // 32 nodes
        int op  = t & 7;                 // 8 output pairs
        long long nd = (long long)blockIdx.x * 32 + nl2;
        if (nd < n) {
            float o0 = 0.f, o1 = 0.f;
#pragma unroll
            for (int k = 0; k < HIDC; ++k) {
                float h = hs[nl2][k];
                o0 = fmaf(h, wl2[k][2 * op],     o0);
                o1 = fmaf(h, wl2[k][2 * op + 1], o1);
            }
            float di = dinv[nd];
            h2b[nd * 8 + op] = bf16pair(o0 * di, o1 * di);
        }
    }
}

// ---------------- layer-2 pull aggregation (8B gathers) -> d_out -----------
// 4 lanes/node, uint2 per lane (4 channels); float4 output write.
__global__ __launch_bounds__(256) void k_agg2csr(const int* __restrict__ ptr,
                                                 const int* __restrict__ cnt,
                                                 const int* __restrict__ csr_src,
                                                 const float* __restrict__ dinv,
                                                 const unsigned* __restrict__ h2b,
                                                 const float* __restrict__ b2,
                                                 float* __restrict__ out, int n) {
    long long g = (long long)blockIdx.x * blockDim.x + threadIdx.x;
    int node = (int)(g >> 2);
    int qp = (int)(g & 3);               // ch 4qp..4qp+3
    if (node >= n) return;
    const uint2* __restrict__ h2v = (const uint2*)h2b;   // 4 uint2 per node
    uint2 us = h2v[(long long)node * 4 + qp];
    float a0 = bf16lo(us.x), a1 = bf16hi(us.x);
    float a2 = bf16lo(us.y), a3 = bf16hi(us.y);
    int st = ptr[node], deg = cnt[node];
    int j = 0;
    for (; j + 3 < deg; j += 4) {
        int s0 = csr_src[st + j], s1 = csr_src[st + j + 1];
        int s2 = csr_src[st + j + 2], s3 = csr_src[st + j + 3];
        uint2 u0 = h2v[(long long)s0 * 4 + qp];
        uint2 u1 = h2v[(long long)s1 * 4 + qp];
        uint2 u2 = h2v[(long long)s2 * 4 + qp];
        uint2 u3 = h2v[(long long)s3 * 4 + qp];
        a0 += (bf16lo(u0.x) + bf16lo(u1.x)) + (bf16lo(u2.x) + bf16lo(u3.x));
        a1 += (bf16hi(u0.x) + bf16hi(u1.x)) + (bf16hi(u2.x) + bf16hi(u3.x));
        a2 += (bf16lo(u0.y) + bf16lo(u1.y)) + (bf16lo(u2.y) + bf16lo(u3.y));
        a3 += (bf16hi(u0.y) + bf16hi(u1.y)) + (bf16hi(u2.y) + bf16hi(u3.y));
    }
    for (; j < deg; ++j) {
        uint2 u = h2v[(long long)csr_src[st + j] * 4 + qp];
        a0 += bf16lo(u.x); a1 += bf16hi(u.x);
        a2 += bf16lo(u.y); a3 += bf16hi(u.y);
    }
    float di = dinv[node];
    *(float4*)(out + (long long)node * OUTC + 4 * qp) =
        make_float4(a0 * di + b2[4 * qp],     a1 * di + b2[4 * qp + 1],
                    a2 * di + b2[4 * qp + 2], a3 * di + b2[4 * qp + 3]);
}

extern "C" void kernel_launch(void* const* d_in, const int* in_sizes, int n_in,
                              void* d_out, int out_size, void* d_ws, size_t ws_size,
                              hipStream_t stream) {
    const float* x  = (const float*)d_in[0];
    const int*   ei = (const int*)d_in[1];
    const float* W1 = (const float*)d_in[2];
    const float* b1 = (const float*)d_in[3];
    const float* W2 = (const float*)d_in[4];
    const float* b2 = (const float*)d_in[5];
    const int n = in_sizes[0] / IN_C;            // 100000
    const long long E = in_sizes[1] / 2;         // 3200000
    float* out = (float*)d_out;

    const int nbkt = (n + NPB - 1) / NPB;        // 391
    const int nsb  = (int)((E + EPB - 1) / EPB); // 261 scatter blocks
    const int ngb  = (n + 255) / 256;            // 391 gemm1 blocks

    char* ws = (char*)d_ws;
    size_t off = 0;
    auto alloc = [&](size_t bytes) { void* p = ws + off; off += (bytes + 255) & ~(size_t)255; return p; };
    int*      flag     = (int*)alloc(256);
    int*      bkt_cur  = (int*)alloc((size_t)MAXBKT * 4);
    float*    dinv     = (float*)alloc((size_t)n * 4);
    int*      cnt      = (int*)alloc((size_t)n * 4);
    int*      ptr      = (int*)alloc((size_t)n * 4);
    unsigned* packed   = (unsigned*)alloc((size_t)nbkt * CAP * 4);        // 25.6 MB
    int*      csr_src  = (int*)alloc((size_t)nbkt * CAP * 4);             // 25.6 MB
    unsigned short* wf = (unsigned short*)alloc(8 * 2 * 2 * 64 * 8 * 2);  // 32 KB
    unsigned* h1b      = (unsigned*)alloc((size_t)n * (HIDC / 2) * 4);    // bf16 [n][32]
    unsigned* h2b      = (unsigned*)alloc((size_t)n * (OUTC / 2) * 4);    // bf16 [n][16]

    k_init<<<9, 256, 0, stream>>>(ei, flag, bkt_cur, nbkt, W1, wf);
    k_super<<<nsb + ngb, 1024, 0, stream>>>(ei, E, flag, bkt_cur, packed, nbkt, nsb,
                                            x, wf, (unsigned short*)h1b, n);
    k_bucket_csr<<<nbkt, NPB, 0, stream>>>(packed, bkt_cur, csr_src, ptr, cnt, dinv, h1b, n);
    k_agg1g2<<<(n + 31) / 32, 256, 0, stream>>>(ptr, cnt, csr_src, dinv, h1b, b1, W2, h2b, n);
    k_agg2csr<<<(int)(((long long)n * 4 + 255) / 256), 256, 0, stream>>>(
        ptr, cnt, csr_src, dinv, h2b, b2, out, n);
}